// Round 6
// baseline (1141.817 us; speedup 1.0000x reference)
//
#include <hip/hip_runtime.h>
#include <math.h>

#define NN 20000
#define NE 320000
#define D 50
#define TOWERS 5
#define TD 250      // TOWERS*D
#define ASTR 256    // padded row stride for ai/aj (float4-friendly)
#define AGGSTR 1000 // packed agg row: [t*200 + plane*50 + g]
#define FOUT 10
#define EPS 1e-5f

// ------------------------------------------------------------------ setup
__global__ void k_deg(const int* __restrict__ dst, int* __restrict__ deg) {
    int e = blockIdx.x * 256 + threadIdx.x;
    if (e < NE) atomicAdd(&deg[dst[e]], 1);
}

__global__ void k_scan(const int* __restrict__ deg, int* __restrict__ offs) {
    __shared__ int buf[1024];
    __shared__ int carry;
    int tid = threadIdx.x;
    if (tid == 0) carry = 0;
    __syncthreads();
    for (int base = 0; base < NN; base += 1024) {
        int i = base + tid;
        int v = (i < NN) ? deg[i] : 0;
        buf[tid] = v;
        __syncthreads();
        for (int off = 1; off < 1024; off <<= 1) {
            int t = (tid >= off) ? buf[tid - off] : 0;
            __syncthreads();
            buf[tid] += t;
            __syncthreads();
        }
        int excl = carry + buf[tid] - v;   // exclusive prefix
        if (i < NN) offs[i] = excl;
        __syncthreads();
        if (tid == 0) carry += buf[1023];
        __syncthreads();
    }
    if (tid == 0) offs[NN] = carry;        // == NE
}

__global__ void k_csr(const int* __restrict__ src, const int* __restrict__ dst,
                      const int* __restrict__ offs, int* __restrict__ cursor,
                      int* __restrict__ csr_src) {
    int e = blockIdx.x * 256 + threadIdx.x;
    if (e < NE) {
        int d = dst[e];
        int slot = atomicAdd(&cursor[d], 1);
        csr_src[offs[d] + slot] = src[e];
    }
}

__global__ void k_avglog(const int* __restrict__ deg, float* __restrict__ accum) {
    int n = blockIdx.x * 256 + threadIdx.x;
    float v = (n < NN) ? logf((float)deg[n] + 1.0f) : 0.0f;
    for (int o = 32; o > 0; o >>= 1) v += __shfl_down(v, o);
    __shared__ float wsum[4];
    int lane = threadIdx.x & 63, w = threadIdx.x >> 6;
    if (lane == 0) wsum[w] = v;
    __syncthreads();
    if (threadIdx.x == 0) atomicAdd(accum, wsum[0] + wsum[1] + wsum[2] + wsum[3]);
}

__global__ void k_emb(const int* __restrict__ x, const float* __restrict__ emb,
                      float* __restrict__ h) {
    int idx = blockIdx.x * 256 + threadIdx.x;
    if (idx < NN * D) {
        int n = idx / D, c = idx % D;
        h[idx] = emb[x[n] * D + c];
    }
}

// ------------------------------------------------------------- per layer
#define PRE_NT 64
__global__ __launch_bounds__(256) void k_pre(const float* __restrict__ h,
                                             const float* __restrict__ preW, // [TD][2D]
                                             float* __restrict__ ai,
                                             float* __restrict__ aj) {
    __shared__ float xl[PRE_NT * 52];
    int n0 = blockIdx.x * PRE_NT;
    int nmax = min(PRE_NT, NN - n0);
    for (int k = threadIdx.x; k < nmax * D; k += 256) {
        int nl = k / D, f = k % D;
        xl[nl * 52 + f] = h[(n0 + nl) * D + f];
    }
    __syncthreads();
    int o = threadIdx.x;
    if (o < TD) {
        const float* w0 = preW + o * (2 * D);
        float wi[D], wj[D];
#pragma unroll
        for (int f = 0; f < D; ++f) { wi[f] = w0[f]; wj[f] = w0[D + f]; }
        for (int nl = 0; nl < nmax; ++nl) {
            const float* xv = &xl[nl * 52];
            float a0 = 0.f, a1 = 0.f;
#pragma unroll
            for (int f = 0; f < D; ++f) { a0 += xv[f] * wi[f]; a1 += xv[f] * wj[f]; }
            ai[(size_t)(n0 + nl) * ASTR + o] = a0;
            aj[(size_t)(n0 + nl) * ASTR + o] = a1;
        }
    } else if (o < ASTR) {                    // zero-fill pad columns
        for (int nl = 0; nl < nmax; ++nl) {
            ai[(size_t)(n0 + nl) * ASTR + o] = 0.f;
            aj[(size_t)(n0 + nl) * ASTR + o] = 0.f;
        }
    }
}

// Edge aggregation, feature-sliced for L2 locality (chunk = blockIdx.x & 7).
// Wave handles 8 nodes x 32 features (lane = g*8+q). Writes PACKED agg rows
// [n][t*200 + plane*50 + g] with the (ai + preB) base already folded into
// mean/min/max (skipped when deg==0, matching torch_scatter empty fill).
__global__ __launch_bounds__(512) void k_agg(
    const float* __restrict__ aj, const int* __restrict__ offs,
    const int* __restrict__ csr_src, const float* __restrict__ ai,
    const float* __restrict__ preB, float* __restrict__ agg) {
    int chunk = blockIdx.x & 7;
    int nb = blockIdx.x >> 3;
    int tid = threadIdx.x;
    int wave = tid >> 6, lane = tid & 63;
    int g = lane >> 3, q = lane & 7;
    int n = nb * 64 + wave * 8 + g;
    bool node_ok = n < NN;
    int e0 = 0, deg = 0;
    if (node_ok) { e0 = offs[n]; deg = offs[n + 1] - e0; }
    int mdeg = deg;
    mdeg = min(mdeg, __shfl_xor(mdeg, 8));
    mdeg = min(mdeg, __shfl_xor(mdeg, 16));
    mdeg = min(mdeg, __shfl_xor(mdeg, 32));   // wave-min degree

    const float4* ajv = (const float4*)aj;    // row stride 64 float4
    int coloff = chunk * 8 + q;               // float4 column in row
    float s1x = 0.f, s1y = 0.f, s1z = 0.f, s1w = 0.f;
    float s2x = 0.f, s2y = 0.f, s2z = 0.f, s2w = 0.f;
    float mnx = INFINITY, mny = INFINITY, mnz = INFINITY, mnw = INFINITY;
    float mxx = -INFINITY, mxy = -INFINITY, mxz = -INFINITY, mxw = -INFINITY;

    int it = 0;
    for (; it < mdeg; ++it) {                 // unmasked: all groups valid
        int s = csr_src[e0 + it];
        float4 v = ajv[(size_t)s * 64 + coloff];
        s1x += v.x; s1y += v.y; s1z += v.z; s1w += v.w;
        s2x = fmaf(v.x, v.x, s2x); s2y = fmaf(v.y, v.y, s2y);
        s2z = fmaf(v.z, v.z, s2z); s2w = fmaf(v.w, v.w, s2w);
        mnx = fminf(mnx, v.x); mny = fminf(mny, v.y);
        mnz = fminf(mnz, v.z); mnw = fminf(mnw, v.w);
        mxx = fmaxf(mxx, v.x); mxy = fmaxf(mxy, v.y);
        mxz = fmaxf(mxz, v.z); mxw = fmaxf(mxw, v.w);
    }
    while (__any(it < deg)) {                 // masked tail (degree imbalance)
        bool valid = it < deg;
        int ee = valid ? e0 + it : 0;
        int s = csr_src[ee];
        float4 v = ajv[(size_t)s * 64 + coloff];
        float zx = valid ? v.x : 0.f, zy = valid ? v.y : 0.f;
        float zz = valid ? v.z : 0.f, zw = valid ? v.w : 0.f;
        s1x += zx; s1y += zy; s1z += zz; s1w += zw;
        s2x = fmaf(zx, zx, s2x); s2y = fmaf(zy, zy, s2y);
        s2z = fmaf(zz, zz, s2z); s2w = fmaf(zw, zw, s2w);
        mnx = fminf(mnx, valid ? v.x : INFINITY);
        mny = fminf(mny, valid ? v.y : INFINITY);
        mnz = fminf(mnz, valid ? v.z : INFINITY);
        mnw = fminf(mnw, valid ? v.w : INFINITY);
        mxx = fmaxf(mxx, valid ? v.x : -INFINITY);
        mxy = fmaxf(mxy, valid ? v.y : -INFINITY);
        mxz = fmaxf(mxz, valid ? v.z : -INFINITY);
        mxw = fmaxf(mxw, valid ? v.w : -INFINITY);
        ++it;
    }

    if (node_ok) {
        float inv = 1.0f / (float)max(deg, 1);
        float m1a[4], mna[4], mxa[4], sda[4];
        m1a[0] = s1x * inv; m1a[1] = s1y * inv; m1a[2] = s1z * inv; m1a[3] = s1w * inv;
        sda[0] = sqrtf(fmaxf(s2x * inv - m1a[0] * m1a[0], 0.f) + EPS);
        sda[1] = sqrtf(fmaxf(s2y * inv - m1a[1] * m1a[1], 0.f) + EPS);
        sda[2] = sqrtf(fmaxf(s2z * inv - m1a[2] * m1a[2], 0.f) + EPS);
        sda[3] = sqrtf(fmaxf(s2w * inv - m1a[3] * m1a[3], 0.f) + EPS);
        mna[0] = mnx; mna[1] = mny; mna[2] = mnz; mna[3] = mnw;
        mxa[0] = mxx; mxa[1] = mxy; mxa[2] = mxz; mxa[3] = mxw;
        int f0 = coloff * 4;
        float4 aiv = ((const float4*)ai)[(size_t)n * 64 + coloff];
        float aia[4] = {aiv.x, aiv.y, aiv.z, aiv.w};
#pragma unroll
        for (int k = 0; k < 4; ++k) {
            int f = f0 + k;
            if (f < TD) {
                float base;
                if (deg > 0) {
                    base = aia[k] + preB[f];
                } else {
                    base = 0.f;
                    m1a[k] = 0.f; mna[k] = 0.f; mxa[k] = 0.f;
                    // sda[k] already sqrt(EPS)
                }
                int t = f / 50, gg = f - t * 50;
                float* row = agg + (size_t)n * AGGSTR + t * 200 + gg;
                row[0]   = m1a[k] + base;
                row[50]  = mna[k] + base;
                row[100] = mxa[k] + base;
                row[150] = sda[k];
            }
        }
    }
}

// post-NN + lin + BN-stats. 16 nodes/block, 512 threads.
// Dot phase: threads 0..399 = (o:50, g:8) with half=g&1 (node octet) and
// jq=g>>2? no: jq=g>>1 (j-quarter). Each thread reads its agg float4 ONCE
// and dots it against all 3 scaler sections (identity/amp/atten), folding
// sc/isc per node -> dp[jq][m][o]. Threads 400..499 do the x-part from
// global h -> dp[4][m][o]. w rows read only 2x per block (amortized).
#define NT 16
__global__ __launch_bounds__(512) void k_post(
    const float* __restrict__ h, const float* __restrict__ agg,
    const int* __restrict__ offs,
    const float* __restrict__ postW,  // [T][FOUT][650]
    const float* __restrict__ postB,  // [50]
    const float* __restrict__ linW,   // [50][50]
    const float* __restrict__ linB,   // [50]
    const float* __restrict__ avg_accum, float* __restrict__ hraw,
    float* __restrict__ bn) {
    __shared__ float ag[NT * AGGSTR];   // 64 KB; reused as yr after dots
    __shared__ float dp[5][NT][50];     // partials: jq 0..3 (scaled), 4 = x
    __shared__ float scs[NT], iscs[NT];
    __shared__ float bnl[100];
    int n0 = blockIdx.x * NT;
    int tid = threadIdx.x;

    const float4* av4 = (const float4*)(agg + (size_t)n0 * AGGSTR);
    float4* ag4 = (float4*)ag;
    for (int i = tid; i < NT * (AGGSTR / 4); i += 512) ag4[i] = av4[i];
    if (tid < NT) {
        int n = n0 + tid;
        int dg = offs[n + 1] - offs[n];
        float cnt = (float)max(dg, 1);
        float avg = avg_accum[0] * (1.0f / NN);
        float sc = logf(cnt + 1.0f) / avg;
        scs[tid] = sc;
        iscs[tid] = 1.0f / sc;
    }
    if (tid < 100) bnl[tid] = 0.f;
    __syncthreads();

    if (tid < 400) {
        // agg dots, p-merged: (o, half, jq) -> 8 nodes
        const int jb[5] = {0, 13, 26, 38, 50};
        int o = tid % 50;
        int g = tid / 50;
        int half = g & 1, jq = g >> 1;
        int t = o / FOUT;
        int m0 = half * 8;
        const float* wrow = postW + o * 650 + 50;   // 3 x 200 sections
        float a1[8], a2[8], a3[8];
#pragma unroll
        for (int i = 0; i < 8; ++i) { a1[i] = 0.f; a2[i] = 0.f; a3[i] = 0.f; }
        const float* agt = ag + t * 200;
        for (int j = jb[jq]; j < jb[jq + 1]; ++j) {
            const float2* w1 = (const float2*)(wrow + 4 * j);
            const float2* w2 = (const float2*)(wrow + 200 + 4 * j);
            const float2* w3 = (const float2*)(wrow + 400 + 4 * j);
            float2 w1a = w1[0], w1b = w1[1];
            float2 w2a = w2[0], w2b = w2[1];
            float2 w3a = w3[0], w3b = w3[1];
#pragma unroll
            for (int i = 0; i < 8; ++i) {
                float4 a = *(const float4*)&agt[(m0 + i) * AGGSTR + 4 * j];
                a1[i] += a.x * w1a.x + a.y * w1a.y + a.z * w1b.x + a.w * w1b.y;
                a2[i] += a.x * w2a.x + a.y * w2a.y + a.z * w2b.x + a.w * w2b.y;
                a3[i] += a.x * w3a.x + a.y * w3a.y + a.z * w3b.x + a.w * w3b.y;
            }
        }
#pragma unroll
        for (int i = 0; i < 8; ++i) {
            int m = m0 + i;
            dp[jq][m][o] = a1[i] + scs[m] * a2[i] + iscs[m] * a3[i];
        }
    } else if (tid < 500) {
        // x part: (o, half) -> 8 nodes, x streamed from global (L2-hot)
        int r = tid - 400;
        int o = r % 50;
        int half = r / 50;
        int m0 = half * 8;
        const float2* w2 = (const float2*)(postW + o * 650);
        float acc[8];
#pragma unroll
        for (int i = 0; i < 8; ++i) acc[i] = 0.f;
        for (int j = 0; j < 25; ++j) {
            float2 w = w2[j];
#pragma unroll
            for (int i = 0; i < 8; ++i) {
                float2 xv = *(const float2*)&h[(size_t)(n0 + m0 + i) * 50 + 2 * j];
                acc[i] += xv.x * w.x + xv.y * w.y;
            }
        }
#pragma unroll
        for (int i = 0; i < 8; ++i) dp[4][m0 + i][o] = acc[i];
    }
    __syncthreads();

    float* yr = ag;                     // ag is dead; reuse as y buffer
    for (int k = tid; k < NT * 50; k += 512) {
        int nl = k / 50, o = k - nl * 50;
        yr[k] = postB[o] + dp[0][nl][o] + dp[1][nl][o] + dp[2][nl][o]
              + dp[3][nl][o] + dp[4][nl][o];
    }
    __syncthreads();

    for (int k = tid; k < NT * 50; k += 512) {
        int nl = k / 50, c = k - nl * 50;
        const float2* w2 = (const float2*)(linW + c * 50);
        const float2* yv = (const float2*)(yr + nl * 50);
        float acc = linB[c];
#pragma unroll
        for (int q = 0; q < 25; ++q) {
            float2 a = yv[q], b = w2[q];
            acc += a.x * b.x + a.y * b.y;
        }
        hraw[(n0 + nl) * 50 + c] = acc;
        atomicAdd(&bnl[c], acc);
        atomicAdd(&bnl[50 + c], acc * acc);
    }
    __syncthreads();
    if (tid < 100) atomicAdd(&bn[tid], bnl[tid]);
}

__global__ void k_bnapply(const float* __restrict__ hraw, const float* __restrict__ bn,
                          const float* __restrict__ gamma, const float* __restrict__ beta,
                          float* __restrict__ h) {
    int idx = blockIdx.x * 256 + threadIdx.x;
    if (idx < NN * D) {
        int c = idx % D;
        float mean = bn[c] * (1.0f / NN);
        float var = bn[50 + c] * (1.0f / NN) - mean * mean;
        float v = gamma[c] * (hraw[idx] - mean) * rsqrtf(var + EPS) + beta[c];
        h[idx] = fmaxf(v, 0.f);
    }
}

__global__ void k_mlp(const float* __restrict__ h, const float* __restrict__ W1,
                      const float* __restrict__ b1, const float* __restrict__ W2,
                      const float* __restrict__ b2, float* __restrict__ out) {
    int n = blockIdx.x * 256 + threadIdx.x;
    if (n >= NN) return;
    float hv[50];
#pragma unroll
    for (int f = 0; f < 50; ++f) hv[f] = h[n * 50 + f];
    float s = b2[0];
    for (int o = 0; o < 25; ++o) {
        float a = b1[o];
        const float* w = W1 + o * 50;
#pragma unroll
        for (int f = 0; f < 50; ++f) a += w[f] * hv[f];
        s += W2[o] * fmaxf(a, 0.f);
    }
    out[n] = 1.0f / (1.0f + expf(-s));
}

// ------------------------------------------------------------------ launch
extern "C" void kernel_launch(void* const* d_in, const int* in_sizes, int n_in,
                              void* d_out, int out_size, void* d_ws, size_t ws_size,
                              hipStream_t stream) {
    const int* x = (const int*)d_in[0];
    const int* ei = (const int*)d_in[1];
    const int* src = ei;
    const int* dst = ei + NE;
    const float* emb   = (const float*)d_in[4];
    const float* preW  = (const float*)d_in[5];
    const float* preB  = (const float*)d_in[6];
    const float* postW = (const float*)d_in[7];
    const float* postB = (const float*)d_in[8];
    const float* linW  = (const float*)d_in[9];
    const float* linB  = (const float*)d_in[10];
    const float* gamma = (const float*)d_in[11];
    const float* beta  = (const float*)d_in[12];
    const float* W1 = (const float*)d_in[13];
    const float* b1 = (const float*)d_in[14];
    const float* W2 = (const float*)d_in[15];
    const float* b2 = (const float*)d_in[16];
    float* outp = (float*)d_out;

    char* wsp = (char*)d_ws;
    size_t off = 0;
    auto alloc = [&](size_t bytes) {
        void* p = wsp + off;
        off = (off + bytes + 1023) & ~(size_t)1023;
        return p;
    };
    int* deg    = (int*)alloc(NN * 4);
    int* cursor = (int*)alloc(NN * 4);
    int* offs   = (int*)alloc((NN + 1) * 4);
    int* csr    = (int*)alloc(NE * 4);
    float* bn   = (float*)alloc(512);          // [0:50) sum, [50:100) sq, [100] avg_log
    float* h    = (float*)alloc((size_t)NN * D * 4);
    float* hraw = (float*)alloc((size_t)NN * D * 4);
    float* ai   = (float*)alloc((size_t)NN * ASTR * 4);
    float* aj   = (float*)alloc((size_t)NN * ASTR * 4);
    float* agg  = (float*)alloc((size_t)NN * AGGSTR * 4);  // packed stats+base
    (void)ws_size; (void)in_sizes; (void)n_in; (void)out_size;

    hipMemsetAsync(deg, 0, NN * 4, stream);
    hipMemsetAsync(cursor, 0, NN * 4, stream);
    hipMemsetAsync(bn, 0, 512, stream);

    k_deg<<<(NE + 255) / 256, 256, 0, stream>>>(dst, deg);
    k_scan<<<1, 1024, 0, stream>>>(deg, offs);
    k_csr<<<(NE + 255) / 256, 256, 0, stream>>>(src, dst, offs, cursor, csr);
    k_avglog<<<(NN + 255) / 256, 256, 0, stream>>>(deg, bn + 100);
    k_emb<<<(NN * D + 255) / 256, 256, 0, stream>>>(x, emb, h);

    int aggblocks = ((NN + 63) / 64) * 8;     // nodeblocks x 8 chunks
    for (int l = 0; l < 4; ++l) {
        k_pre<<<(NN + PRE_NT - 1) / PRE_NT, 256, 0, stream>>>(h, preW + l * TD * 100, ai, aj);
        k_agg<<<aggblocks, 512, 0, stream>>>(aj, offs, csr, ai, preB + l * TD, agg);
        hipMemsetAsync(bn, 0, 400, stream);   // keep bn[100] (avg_log) intact
        k_post<<<NN / NT, 512, 0, stream>>>(h, agg, offs,
                                            postW + l * 32500, postB + l * 50,
                                            linW + l * 2500, linB + l * 50,
                                            bn + 100, hraw, bn);
        k_bnapply<<<(NN * D + 255) / 256, 256, 0, stream>>>(hraw, bn, gamma + l * 50,
                                                            beta + l * 50, h);
    }
    k_mlp<<<(NN + 255) / 256, 256, 0, stream>>>(h, W1, b1, W2, b2, outp);
}

// Round 7
// 1074.212 us; speedup vs baseline: 1.0629x; 1.0629x over previous
//
#include <hip/hip_runtime.h>
#include <math.h>

#define NN 20000
#define NNP 20224   // padded to 79*256
#define NGRP 79
#define NE 320000
#define D 50
#define TOWERS 5
#define TD 250      // TOWERS*D
#define ASTR 256    // padded row stride for ai/aj (float4-friendly)
#define FOUT 10
#define EPS 1e-5f

// ------------------------------------------------------------------ setup
__global__ void k_deg(const int* __restrict__ dst, int* __restrict__ deg) {
    int e = blockIdx.x * 256 + threadIdx.x;
    if (e < NE) atomicAdd(&deg[dst[e]], 1);
}

__global__ void k_scan(const int* __restrict__ deg, int* __restrict__ offs) {
    __shared__ int buf[1024];
    __shared__ int carry;
    int tid = threadIdx.x;
    if (tid == 0) carry = 0;
    __syncthreads();
    for (int base = 0; base < NN; base += 1024) {
        int i = base + tid;
        int v = (i < NN) ? deg[i] : 0;
        buf[tid] = v;
        __syncthreads();
        for (int off = 1; off < 1024; off <<= 1) {
            int t = (tid >= off) ? buf[tid - off] : 0;
            __syncthreads();
            buf[tid] += t;
            __syncthreads();
        }
        int excl = carry + buf[tid] - v;   // exclusive prefix
        if (i < NN) offs[i] = excl;
        __syncthreads();
        if (tid == 0) carry += buf[1023];
        __syncthreads();
    }
    if (tid == 0) offs[NN] = carry;        // == NE
}

__global__ void k_csr(const int* __restrict__ src, const int* __restrict__ dst,
                      const int* __restrict__ offs, int* __restrict__ cursor,
                      int* __restrict__ csr_src) {
    int e = blockIdx.x * 256 + threadIdx.x;
    if (e < NE) {
        int d = dst[e];
        int slot = atomicAdd(&cursor[d], 1);
        csr_src[offs[d] + slot] = src[e];
    }
}

__global__ void k_avglog(const int* __restrict__ deg, float* __restrict__ accum) {
    int n = blockIdx.x * 256 + threadIdx.x;
    float v = (n < NN) ? logf((float)deg[n] + 1.0f) : 0.0f;
    for (int o = 32; o > 0; o >>= 1) v += __shfl_down(v, o);
    __shared__ float wsum[4];
    int lane = threadIdx.x & 63, w = threadIdx.x >> 6;
    if (lane == 0) wsum[w] = v;
    __syncthreads();
    if (threadIdx.x == 0) atomicAdd(accum, wsum[0] + wsum[1] + wsum[2] + wsum[3]);
}

// embedding -> hT (feature-major), zero-filled padding columns
__global__ void k_emb(const int* __restrict__ x, const float* __restrict__ emb,
                      float* __restrict__ hT) {
    int idx = blockIdx.x * 256 + threadIdx.x;
    if (idx < D * NNP) {
        int c = idx / NNP, n = idx % NNP;
        hT[idx] = (n < NN) ? emb[x[n] * D + c] : 0.f;
    }
}

// ------------------------------------------------------------- per layer
// ai/aj row-major padded to ASTR, from hT-staged x tile.
#define PRE_NT 64
__global__ __launch_bounds__(256) void k_pre(const float* __restrict__ hT,
                                             const float* __restrict__ preW, // [TD][2D]
                                             float* __restrict__ ai,
                                             float* __restrict__ aj) {
    __shared__ float xl[PRE_NT * 52];
    int n0 = blockIdx.x * PRE_NT;
    int nmax = min(PRE_NT, NN - n0);
    for (int k = threadIdx.x; k < PRE_NT * D; k += 256) {
        int f = k >> 6, nl = k & 63;               // hT pad cols are 0
        xl[nl * 52 + f] = hT[(size_t)f * NNP + n0 + nl];
    }
    __syncthreads();
    int o = threadIdx.x;
    if (o < TD) {
        const float* w0 = preW + o * (2 * D);
        float wi[D], wj[D];
#pragma unroll
        for (int f = 0; f < D; ++f) { wi[f] = w0[f]; wj[f] = w0[D + f]; }
        for (int nl = 0; nl < nmax; ++nl) {
            const float* xv = &xl[nl * 52];
            float a0 = 0.f, a1 = 0.f;
#pragma unroll
            for (int f = 0; f < D; ++f) { a0 += xv[f] * wi[f]; a1 += xv[f] * wj[f]; }
            ai[(size_t)(n0 + nl) * ASTR + o] = a0;
            aj[(size_t)(n0 + nl) * ASTR + o] = a1;
        }
    } else if (o < ASTR) {                    // zero-fill pad columns
        for (int nl = 0; nl < nmax; ++nl) {
            ai[(size_t)(n0 + nl) * ASTR + o] = 0.f;
            aj[(size_t)(n0 + nl) * ASTR + o] = 0.f;
        }
    }
}

// Edge aggregation, feature-sliced for L2 locality (chunk = blockIdx.x & 7).
// Wave handles 8 nodes x 32 features (lane = g*8+q). Writes TRANSPOSED agg:
// aggT[t*200 + plane*50 + gg][n], with (ai + preB) base folded into
// mean/min/max (skipped when deg==0, matching torch_scatter empty fill).
__global__ __launch_bounds__(512) void k_agg(
    const float* __restrict__ aj, const int* __restrict__ offs,
    const int* __restrict__ csr_src, const float* __restrict__ ai,
    const float* __restrict__ preB, float* __restrict__ aggT) {
    int chunk = blockIdx.x & 7;
    int nb = blockIdx.x >> 3;
    int tid = threadIdx.x;
    int wave = tid >> 6, lane = tid & 63;
    int g = lane >> 3, q = lane & 7;
    int n = nb * 64 + wave * 8 + g;
    bool node_ok = n < NN;
    int e0 = 0, deg = 0;
    if (node_ok) { e0 = offs[n]; deg = offs[n + 1] - e0; }
    int mdeg = deg;
    mdeg = min(mdeg, __shfl_xor(mdeg, 8));
    mdeg = min(mdeg, __shfl_xor(mdeg, 16));
    mdeg = min(mdeg, __shfl_xor(mdeg, 32));   // wave-min degree

    const float4* ajv = (const float4*)aj;    // row stride 64 float4
    int coloff = chunk * 8 + q;               // float4 column in row
    float s1x = 0.f, s1y = 0.f, s1z = 0.f, s1w = 0.f;
    float s2x = 0.f, s2y = 0.f, s2z = 0.f, s2w = 0.f;
    float mnx = INFINITY, mny = INFINITY, mnz = INFINITY, mnw = INFINITY;
    float mxx = -INFINITY, mxy = -INFINITY, mxz = -INFINITY, mxw = -INFINITY;

    int it = 0;
    for (; it < mdeg; ++it) {                 // unmasked: all groups valid
        int s = csr_src[e0 + it];
        float4 v = ajv[(size_t)s * 64 + coloff];
        s1x += v.x; s1y += v.y; s1z += v.z; s1w += v.w;
        s2x = fmaf(v.x, v.x, s2x); s2y = fmaf(v.y, v.y, s2y);
        s2z = fmaf(v.z, v.z, s2z); s2w = fmaf(v.w, v.w, s2w);
        mnx = fminf(mnx, v.x); mny = fminf(mny, v.y);
        mnz = fminf(mnz, v.z); mnw = fminf(mnw, v.w);
        mxx = fmaxf(mxx, v.x); mxy = fmaxf(mxy, v.y);
        mxz = fmaxf(mxz, v.z); mxw = fmaxf(mxw, v.w);
    }
    while (__any(it < deg)) {                 // masked tail (degree imbalance)
        bool valid = it < deg;
        int ee = valid ? e0 + it : 0;
        int s = csr_src[ee];
        float4 v = ajv[(size_t)s * 64 + coloff];
        float zx = valid ? v.x : 0.f, zy = valid ? v.y : 0.f;
        float zz = valid ? v.z : 0.f, zw = valid ? v.w : 0.f;
        s1x += zx; s1y += zy; s1z += zz; s1w += zw;
        s2x = fmaf(zx, zx, s2x); s2y = fmaf(zy, zy, s2y);
        s2z = fmaf(zz, zz, s2z); s2w = fmaf(zw, zw, s2w);
        mnx = fminf(mnx, valid ? v.x : INFINITY);
        mny = fminf(mny, valid ? v.y : INFINITY);
        mnz = fminf(mnz, valid ? v.z : INFINITY);
        mnw = fminf(mnw, valid ? v.w : INFINITY);
        mxx = fmaxf(mxx, valid ? v.x : -INFINITY);
        mxy = fmaxf(mxy, valid ? v.y : -INFINITY);
        mxz = fmaxf(mxz, valid ? v.z : -INFINITY);
        mxw = fmaxf(mxw, valid ? v.w : -INFINITY);
        ++it;
    }

    if (node_ok) {
        float inv = 1.0f / (float)max(deg, 1);
        float m1a[4], mna[4], mxa[4], sda[4];
        m1a[0] = s1x * inv; m1a[1] = s1y * inv; m1a[2] = s1z * inv; m1a[3] = s1w * inv;
        sda[0] = sqrtf(fmaxf(s2x * inv - m1a[0] * m1a[0], 0.f) + EPS);
        sda[1] = sqrtf(fmaxf(s2y * inv - m1a[1] * m1a[1], 0.f) + EPS);
        sda[2] = sqrtf(fmaxf(s2z * inv - m1a[2] * m1a[2], 0.f) + EPS);
        sda[3] = sqrtf(fmaxf(s2w * inv - m1a[3] * m1a[3], 0.f) + EPS);
        mna[0] = mnx; mna[1] = mny; mna[2] = mnz; mna[3] = mnw;
        mxa[0] = mxx; mxa[1] = mxy; mxa[2] = mxz; mxa[3] = mxw;
        int f0 = coloff * 4;
        float4 aiv = ((const float4*)ai)[(size_t)n * 64 + coloff];
        float aia[4] = {aiv.x, aiv.y, aiv.z, aiv.w};
#pragma unroll
        for (int k = 0; k < 4; ++k) {
            int f = f0 + k;
            if (f < TD) {
                float base;
                if (deg > 0) {
                    base = aia[k] + preB[f];
                } else {
                    base = 0.f;
                    m1a[k] = 0.f; mna[k] = 0.f; mxa[k] = 0.f;
                }
                int t = f / 50, gg = f - t * 50;
                float* col = aggT + (size_t)(t * 200 + gg) * NNP + n;
                col[0]           = m1a[k] + base;
                col[50 * NNP]    = mna[k] + base;
                col[100 * NNP]   = mxa[k] + base;
                col[150 * NNP]   = sda[k];
            }
        }
    }
}

// post-NN, thread-per-node streaming GEMV over transposed agg.
// Grid = NGRP x TOWERS. Each thread: 200-f loop, coalesced aggT column loads,
// wave-uniform LDS weight broadcasts, 30 accumulators (id/amp/atten merged);
// then 50-f x-part from hT; combine with per-node sc/isc -> yT.
__global__ __launch_bounds__(256) void k_post(
    const float* __restrict__ hT, const float* __restrict__ aggT,
    const int* __restrict__ offs,
    const float* __restrict__ postW,  // [T*FOUT][650]
    const float* __restrict__ postB,  // [50]
    const float* __restrict__ avg_accum, float* __restrict__ yT) {
    __shared__ float wlds[200][30];
    __shared__ float wx[50][10];
    __shared__ float bias[10];
    int t = blockIdx.x / NGRP;
    int grp = blockIdx.x - t * NGRP;
    int tid = threadIdx.x;
    int n = grp * 256 + tid;

    for (int i = tid; i < 6000; i += 256) {
        int j = i / 30, r = i - j * 30;
        int p = r / 10, g = r - p * 10;
        wlds[j][r] = postW[(t * FOUT + g) * 650 + 50 + p * 200 + j];
    }
    for (int i = tid; i < 500; i += 256) {
        int j = i / 10, g = i - j * 10;
        wx[j][g] = postW[(t * FOUT + g) * 650 + j];
    }
    if (tid < 10) bias[tid] = postB[t * FOUT + tid];
    __syncthreads();

    float acc[30];
#pragma unroll
    for (int i = 0; i < 30; ++i) acc[i] = 0.f;
    const float* aggcol = aggT + (size_t)(t * 200) * NNP + n;
#pragma unroll 4
    for (int j = 0; j < 200; ++j) {
        float a = aggcol[(size_t)j * NNP];
        const float* w = wlds[j];
#pragma unroll
        for (int g = 0; g < 30; ++g) acc[g] = fmaf(a, w[g], acc[g]);
    }
    float xacc[10];
#pragma unroll
    for (int i = 0; i < 10; ++i) xacc[i] = 0.f;
#pragma unroll 4
    for (int j = 0; j < 50; ++j) {
        float a = hT[(size_t)j * NNP + n];
        const float* w = wx[j];
#pragma unroll
        for (int g = 0; g < 10; ++g) xacc[g] = fmaf(a, w[g], xacc[g]);
    }
    if (n < NN) {
        int dg = offs[n + 1] - offs[n];
        float cnt = (float)max(dg, 1);
        float sc = logf(cnt + 1.0f) / (avg_accum[0] * (1.0f / NN));
        float isc = 1.0f / sc;
#pragma unroll
        for (int g = 0; g < 10; ++g)
            yT[(size_t)(t * FOUT + g) * NNP + n] =
                bias[g] + xacc[g] + acc[g] + sc * acc[10 + g] + isc * acc[20 + g];
    }
}

// 50x50 linear on transposed y -> transposed hraw. Thread per node.
__global__ __launch_bounds__(256) void k_lin(
    const float* __restrict__ yT, const float* __restrict__ linW,
    const float* __restrict__ linB, float* __restrict__ hrawT) {
    __shared__ float wl[2500];
    __shared__ float bl[50];
    int tid = threadIdx.x;
    int n = blockIdx.x * 256 + tid;
    for (int i = tid; i < 2500; i += 256) wl[i] = linW[i];
    if (tid < 50) bl[tid] = linB[tid];
    __syncthreads();
    float y[50];
#pragma unroll
    for (int q = 0; q < 50; ++q) y[q] = yT[(size_t)q * NNP + n];
    for (int c = 0; c < 50; ++c) {
        float a = bl[c];
        const float* w = wl + c * 50;
#pragma unroll
        for (int q = 0; q < 50; ++q) a = fmaf(w[q], y[q], a);
        hrawT[(size_t)c * NNP + n] = a;
    }
}

// BN stats: one block per channel, full-row coalesced reduce (no atomics).
__global__ __launch_bounds__(256) void k_bnstats(const float* __restrict__ hrawT,
                                                 float* __restrict__ bn) {
    int c = blockIdx.x;
    int tid = threadIdx.x;
    const float* row = hrawT + (size_t)c * NNP;
    float s = 0.f, sq = 0.f;
    for (int n = tid; n < NN; n += 256) {
        float v = row[n];
        s += v; sq = fmaf(v, v, sq);
    }
    for (int o = 32; o > 0; o >>= 1) {
        s += __shfl_down(s, o);
        sq += __shfl_down(sq, o);
    }
    __shared__ float ws[4], wq[4];
    int lane = tid & 63, w = tid >> 6;
    if (lane == 0) { ws[w] = s; wq[w] = sq; }
    __syncthreads();
    if (tid == 0) {
        bn[c] = ws[0] + ws[1] + ws[2] + ws[3];
        bn[50 + c] = wq[0] + wq[1] + wq[2] + wq[3];
    }
}

__global__ void k_bnapply(const float* __restrict__ hrawT, const float* __restrict__ bn,
                          const float* __restrict__ gamma, const float* __restrict__ beta,
                          float* __restrict__ hT) {
    int idx = blockIdx.x * 256 + threadIdx.x;
    if (idx < D * NNP) {
        int c = idx / NNP, n = idx % NNP;
        float mean = bn[c] * (1.0f / NN);
        float var = bn[50 + c] * (1.0f / NN) - mean * mean;
        float v = gamma[c] * (hrawT[idx] - mean) * rsqrtf(var + EPS) + beta[c];
        hT[idx] = (n < NN) ? fmaxf(v, 0.f) : 0.f;
    }
}

__global__ void k_mlp(const float* __restrict__ hT, const float* __restrict__ W1,
                      const float* __restrict__ b1, const float* __restrict__ W2,
                      const float* __restrict__ b2, float* __restrict__ out) {
    int n = blockIdx.x * 256 + threadIdx.x;
    if (n >= NN) return;
    float hv[50];
#pragma unroll
    for (int f = 0; f < 50; ++f) hv[f] = hT[(size_t)f * NNP + n];
    float s = b2[0];
    for (int o = 0; o < 25; ++o) {
        float a = b1[o];
        const float* w = W1 + o * 50;
#pragma unroll
        for (int f = 0; f < 50; ++f) a += w[f] * hv[f];
        s += W2[o] * fmaxf(a, 0.f);
    }
    out[n] = 1.0f / (1.0f + expf(-s));
}

// ------------------------------------------------------------------ launch
extern "C" void kernel_launch(void* const* d_in, const int* in_sizes, int n_in,
                              void* d_out, int out_size, void* d_ws, size_t ws_size,
                              hipStream_t stream) {
    const int* x = (const int*)d_in[0];
    const int* ei = (const int*)d_in[1];
    const int* src = ei;
    const int* dst = ei + NE;
    const float* emb   = (const float*)d_in[4];
    const float* preW  = (const float*)d_in[5];
    const float* preB  = (const float*)d_in[6];
    const float* postW = (const float*)d_in[7];
    const float* postB = (const float*)d_in[8];
    const float* linW  = (const float*)d_in[9];
    const float* linB  = (const float*)d_in[10];
    const float* gamma = (const float*)d_in[11];
    const float* beta  = (const float*)d_in[12];
    const float* W1 = (const float*)d_in[13];
    const float* b1 = (const float*)d_in[14];
    const float* W2 = (const float*)d_in[15];
    const float* b2 = (const float*)d_in[16];
    float* outp = (float*)d_out;

    char* wsp = (char*)d_ws;
    size_t off = 0;
    auto alloc = [&](size_t bytes) {
        void* p = wsp + off;
        off = (off + bytes + 1023) & ~(size_t)1023;
        return p;
    };
    int* deg    = (int*)alloc(NN * 4);
    int* cursor = (int*)alloc(NN * 4);
    int* offs   = (int*)alloc((NN + 1) * 4);
    int* csr    = (int*)alloc(NE * 4);
    float* bn   = (float*)alloc(512);          // [0:50) sum, [50:100) sq, [100] avg_log
    float* hT    = (float*)alloc((size_t)D * NNP * 4);
    float* hrawT = (float*)alloc((size_t)D * NNP * 4);
    float* yT    = (float*)alloc((size_t)D * NNP * 4);
    float* ai   = (float*)alloc((size_t)NN * ASTR * 4);
    float* aj   = (float*)alloc((size_t)NN * ASTR * 4);
    float* aggT = (float*)alloc((size_t)1000 * NNP * 4);  // transposed stats+base
    (void)ws_size; (void)in_sizes; (void)n_in; (void)out_size;

    hipMemsetAsync(deg, 0, NN * 4, stream);
    hipMemsetAsync(cursor, 0, NN * 4, stream);
    hipMemsetAsync(bn, 0, 512, stream);

    k_deg<<<(NE + 255) / 256, 256, 0, stream>>>(dst, deg);
    k_scan<<<1, 1024, 0, stream>>>(deg, offs);
    k_csr<<<(NE + 255) / 256, 256, 0, stream>>>(src, dst, offs, cursor, csr);
    k_avglog<<<(NN + 255) / 256, 256, 0, stream>>>(deg, bn + 100);
    k_emb<<<(D * NNP + 255) / 256, 256, 0, stream>>>(x, emb, hT);

    int aggblocks = ((NN + 63) / 64) * 8;     // nodeblocks x 8 chunks
    for (int l = 0; l < 4; ++l) {
        k_pre<<<(NN + PRE_NT - 1) / PRE_NT, 256, 0, stream>>>(hT, preW + l * TD * 100, ai, aj);
        k_agg<<<aggblocks, 512, 0, stream>>>(aj, offs, csr, ai, preB + l * TD, aggT);
        k_post<<<NGRP * TOWERS, 256, 0, stream>>>(hT, aggT, offs,
                                                  postW + l * 32500, postB + l * 50,
                                                  bn + 100, yT);
        k_lin<<<NGRP, 256, 0, stream>>>(yT, linW + l * 2500, linB + l * 50, hrawT);
        k_bnstats<<<50, 256, 0, stream>>>(hrawT, bn);
        k_bnapply<<<(D * NNP + 255) / 256, 256, 0, stream>>>(hrawT, bn, gamma + l * 50,
                                                             beta + l * 50, hT);
    }
    k_mlp<<<(NN + 255) / 256, 256, 0, stream>>>(hT, W1, b1, W2, b2, outp);
}